// Round 1
// baseline (3332.713 us; speedup 1.0000x reference)
//
#include <hip/hip_runtime.h>
#include <math.h>

#define B_  8
#define N_  8192
#define S_  1024
#define K_  32
#define C0_ 64

// ======================= FPS (blocks 0..7) + feature transpose (blocks 8..) =======================
// FPS: one block per batch, 512 threads, 16 points/thread in registers.
// Distances computed with _rn ops in the exact reference association order:
//   d = ((dx*dx + dy*dy) + dz*dz), mind = min(mind, d), argmax tie -> lowest index.
// Transpose: feature [B][64][N] -> featT [B][N][64] so the MLP gather is contiguous.
__global__ __launch_bounds__(512) void fps_tr_kernel(
    const float* __restrict__ xyz, const float* __restrict__ feature,
    float* __restrict__ featT, float* __restrict__ newxyz)
{
    __shared__ float sm[3 * N_ + 32];   // FPS: xs/ys/zs + 2x8 u64 reduce slots; transpose: 64x65 tile
    const int tid = threadIdx.x;

    if (blockIdx.x >= B_) {
        // ---- transpose role ----
        float* tile = sm;                      // 64 n x 65 (pad) c
        int bi = (int)blockIdx.x - B_;
        int bb = bi >> 7;                      // batch
        int n0 = (bi & 127) * 64;              // n tile base
        {
            int cg = tid >> 6, ln = tid & 63;
            const float* fb = feature + (size_t)bb * C0_ * N_;
            #pragma unroll
            for (int i = 0; i < 8; ++i) {
                int c = cg * 8 + i;
                tile[ln * 65 + c] = fb[(size_t)c * N_ + n0 + ln];   // coalesced over ln
            }
        }
        __syncthreads();
        {
            int n = tid >> 3, c0 = (tid & 7) * 8;
            float v[8];
            #pragma unroll
            for (int i = 0; i < 8; ++i) v[i] = tile[n * 65 + c0 + i];
            float* dst = featT + ((size_t)(bb * N_ + n0 + n)) * C0_ + c0;
            *(float4*)dst       = make_float4(v[0], v[1], v[2], v[3]);
            *(float4*)(dst + 4) = make_float4(v[4], v[5], v[6], v[7]);
        }
        return;
    }

    // ---- FPS role ----
    const int b = blockIdx.x;
    float* xs = sm;
    float* ys = sm + N_;
    float* zs = sm + 2 * N_;
    unsigned long long* wredA = (unsigned long long*)(sm + 3 * N_);       // 8 u64
    unsigned long long* wredB = (unsigned long long*)(sm + 3 * N_ + 16);  // 8 u64

    float px[16], py[16], pz[16], mind[16];
    const float* xb = xyz + (size_t)b * N_ * 3;
    #pragma unroll
    for (int j = 0; j < 16; ++j) {
        int n = j * 512 + tid;
        float x = xb[n * 3], y = xb[n * 3 + 1], z = xb[n * 3 + 2];
        px[j] = x; py[j] = y; pz[j] = z;
        xs[n] = x; ys[n] = y; zs[n] = z;
        mind[j] = 1e10f;
    }
    __syncthreads();

    float lx = xs[0], ly = ys[0], lz = zs[0];
    if (tid == 0) {
        float* d0 = newxyz + (size_t)b * S_ * 3;
        d0[0] = lx; d0[1] = ly; d0[2] = lz;
    }
    const int lane = tid & 63, wid = tid >> 6;

    for (int it = 1; it < S_; ++it) {
        // update min-distances and track local argmax (first occurrence on ties)
        float bv = -1.0f; int bj = 0;
        #pragma unroll
        for (int j = 0; j < 16; ++j) {
            float dx = __fsub_rn(px[j], lx);
            float dy = __fsub_rn(py[j], ly);
            float dz = __fsub_rn(pz[j], lz);
            float dd = __fadd_rn(__fadd_rn(__fmul_rn(dx, dx), __fmul_rn(dy, dy)), __fmul_rn(dz, dz));
            float mj = fminf(mind[j], dd);
            mind[j] = mj;
            if (mj > bv) { bv = mj; bj = j; }
        }
        // pack: high = float bits (mind >= 0 so monotone), low = ~n so ties pick smallest n
        unsigned long long best =
            ((unsigned long long)__float_as_uint(bv) << 32) |
            (unsigned long long)(0xFFFFFFFFu - (unsigned)(bj * 512 + tid));
        #pragma unroll
        for (int off = 1; off < 64; off <<= 1) {
            unsigned long long o = __shfl_xor(best, off);
            if (o > best) best = o;
        }
        unsigned long long* wred = (it & 1) ? wredA : wredB;
        if (lane == 0) wred[wid] = best;
        __syncthreads();
        // every thread reduces the 8 wave results (broadcast LDS reads) - no 2nd barrier needed
        unsigned long long g = wred[0];
        #pragma unroll
        for (int w = 1; w < 8; ++w) { unsigned long long o = wred[w]; if (o > g) g = o; }
        int ns = (int)(0xFFFFFFFFu - (unsigned)(g & 0xFFFFFFFFull));
        lx = xs[ns]; ly = ys[ns]; lz = zs[ns];
        if (tid == 0) {
            float* d0 = newxyz + ((size_t)b * S_ + it) * 3;
            d0[0] = lx; d0[1] = ly; d0[2] = lz;
        }
    }
}

// ======================= kNN: one block (256 thr) per query =======================
// d = (||q||^2 + ||p||^2) - 2*dot, reference association order, _rn ops.
// Tournament top-32: per-thread best, block reduce, only the winner rescans.
__global__ __launch_bounds__(256) void knn_kernel(
    const float* __restrict__ xyz, const float* __restrict__ newxyz,
    int* __restrict__ nidx)
{
    const int tid = threadIdx.x;
    const int b = blockIdx.x >> 10, s = blockIdx.x & 1023;

    const float* q = newxyz + (size_t)(b * S_ + s) * 3;
    float qx = q[0], qy = q[1], qz = q[2];
    float sa = __fadd_rn(__fadd_rn(__fmul_rn(qx, qx), __fmul_rn(qy, qy)), __fmul_rn(qz, qz));

    float d[32];
    const float* base = xyz + (size_t)b * N_ * 3;
    #pragma unroll
    for (int i = 0; i < 32; ++i) {
        int n = i * 256 + tid;
        float x = base[n * 3], y = base[n * 3 + 1], z = base[n * 3 + 2];
        float sb  = __fadd_rn(__fadd_rn(__fmul_rn(x, x), __fmul_rn(y, y)), __fmul_rn(z, z));
        float dot = __fadd_rn(__fadd_rn(__fmul_rn(qx, x), __fmul_rn(qy, y)), __fmul_rn(qz, z));
        d[i] = __fsub_rn(__fadd_rn(sa, sb), __fmul_rn(2.0f, dot));
    }
    float bd = INFINITY; int bn = 0x7fffffff;
    #pragma unroll
    for (int i = 0; i < 32; ++i) { if (d[i] < bd) { bd = d[i]; bn = i * 256 + tid; } }

    __shared__ float wd_s[4];
    __shared__ int   wn_s[4];
    __shared__ int   seln;
    const int lane = tid & 63, wid = tid >> 6;
    int* out_row = nidx + (size_t)(b * S_ + s) * K_;

    for (int r = 0; r < K_; ++r) {
        float rd = bd; int rn = bn;
        #pragma unroll
        for (int off = 1; off < 64; off <<= 1) {
            float od = __shfl_xor(rd, off);
            int   on = __shfl_xor(rn, off);
            if (od < rd || (od == rd && on < rn)) { rd = od; rn = on; }
        }
        if (lane == 0) { wd_s[wid] = rd; wn_s[wid] = rn; }
        __syncthreads();
        if (tid == 0) {
            float fd = wd_s[0]; int fn = wn_s[0];
            #pragma unroll
            for (int w = 1; w < 4; ++w) {
                float od = wd_s[w]; int on = wn_s[w];
                if (od < fd || (od == fd && on < fn)) { fd = od; fn = on; }
            }
            seln = fn;
            out_row[r] = fn;
        }
        __syncthreads();
        int wn = seln;
        if (bn == wn) {          // owner: remove winner, rescan my 32
            int widx = wn >> 8;
            #pragma unroll
            for (int i = 0; i < 32; ++i) if (i == widx) d[i] = INFINITY;
            bd = INFINITY; bn = 0x7fffffff;
            #pragma unroll
            for (int i = 0; i < 32; ++i) { if (d[i] < bd) { bd = d[i]; bn = i * 256 + tid; } }
        }
    }
}

// ======================= MLP: one block (256 thr) per (b,s) =======================
// X in LDS [k][c] stride 132 (b128-aligned, kg-broadcast). Thread tile MTx4 (o x k).
// og = tid & 31 (32 o-groups), kg = tid >> 5 (8 k-groups of 4).
template<int MT, int KD, bool LAST>
__device__ __forceinline__ void layer(
    const float* __restrict__ Xin, float* __restrict__ Xout,
    const float* __restrict__ W,
    const float* __restrict__ bias, const float* __restrict__ gam,
    const float* __restrict__ bet,  const float* __restrict__ mu,
    const float* __restrict__ var,  int tid)
{
    const int og = tid & 31;
    const int kg = tid >> 5;
    const int o0 = og * MT;
    float acc[MT][4];
    #pragma unroll
    for (int a = 0; a < MT; ++a)
        #pragma unroll
        for (int c = 0; c < 4; ++c) acc[a][c] = 0.f;

    for (int c = 0; c < KD; c += 4) {
        float4 xv[4];
        #pragma unroll
        for (int kk = 0; kk < 4; ++kk)
            xv[kk] = *(const float4*)(Xin + (kg * 4 + kk) * 132 + c);
        #pragma unroll
        for (int oo = 0; oo < MT; ++oo) {
            float4 wv = *(const float4*)(W + (size_t)(o0 + oo) * KD + c);
            #pragma unroll
            for (int kk = 0; kk < 4; ++kk) {
                acc[oo][kk] = fmaf(wv.x, xv[kk].x, acc[oo][kk]);
                acc[oo][kk] = fmaf(wv.y, xv[kk].y, acc[oo][kk]);
                acc[oo][kk] = fmaf(wv.z, xv[kk].z, acc[oo][kk]);
                acc[oo][kk] = fmaf(wv.w, xv[kk].w, acc[oo][kk]);
            }
        }
    }
    float sc[MT], sh[MT];
    #pragma unroll
    for (int oo = 0; oo < MT; ++oo) {
        int o = o0 + oo;
        float sv = gam[o] / sqrtf(var[o] + 1e-5f);
        sc[oo] = sv;
        sh[oo] = (bias[o] - mu[o]) * sv + bet[o];
    }
    if (LAST) {
        // fold k-max of this thread's 4 columns; write [kg][o] for cross-kg reduce
        #pragma unroll
        for (int oo = 0; oo < MT; ++oo) {
            float m = 0.f;  // ReLU output >= 0
            #pragma unroll
            for (int kk = 0; kk < 4; ++kk)
                m = fmaxf(m, fmaxf(fmaf(acc[oo][kk], sc[oo], sh[oo]), 0.f));
            Xout[kg * 256 + o0 + oo] = m;
        }
    } else {
        #pragma unroll
        for (int kk = 0; kk < 4; ++kk) {
            float4 v;
            v.x = fmaxf(fmaf(acc[0][kk], sc[0], sh[0]), 0.f);
            v.y = fmaxf(fmaf(acc[1][kk], sc[1], sh[1]), 0.f);
            v.z = fmaxf(fmaf(acc[2][kk], sc[2], sh[2]), 0.f);
            v.w = fmaxf(fmaf(acc[3][kk], sc[3], sh[3]), 0.f);
            *(float4*)(Xout + (kg * 4 + kk) * 132 + o0) = v;
        }
    }
}

__global__ __launch_bounds__(256) void mlp_kernel(
    const float* __restrict__ featT, const float* __restrict__ feature,
    const int* __restrict__ nidx,
    const float* __restrict__ w0, const float* __restrict__ b0,
    const float* __restrict__ g0, const float* __restrict__ be0,
    const float* __restrict__ m0, const float* __restrict__ v0,
    const float* __restrict__ w1, const float* __restrict__ b1,
    const float* __restrict__ g1, const float* __restrict__ be1,
    const float* __restrict__ m1, const float* __restrict__ v1,
    const float* __restrict__ w2, const float* __restrict__ b2,
    const float* __restrict__ g2, const float* __restrict__ be2,
    const float* __restrict__ m2, const float* __restrict__ v2,
    float* __restrict__ out, int use_featT)
{
    __shared__ float Xa[32 * 132];
    __shared__ float Xb[32 * 132];
    __shared__ int   nid_s[K_];
    const int tid = threadIdx.x;
    const int b = blockIdx.x >> 10, s = blockIdx.x & 1023;

    if (tid < K_) nid_s[tid] = nidx[(size_t)(b * S_ + s) * K_ + tid];
    __syncthreads();

    if (use_featT) {
        int k = tid >> 3, c0 = (tid & 7) * 8;
        const float* src = featT + ((size_t)(b * N_ + nid_s[k])) * C0_ + c0;
        float4 a = *(const float4*)src;
        float4 c = *(const float4*)(src + 4);
        *(float4*)(Xa + k * 132 + c0)     = a;
        *(float4*)(Xa + k * 132 + c0 + 4) = c;
    } else {
        for (int idx = tid; idx < K_ * C0_; idx += 256) {
            int k = idx & 31, c = idx >> 5;
            Xa[k * 132 + c] = feature[((size_t)b * C0_ + c) * N_ + nid_s[k]];
        }
    }
    __syncthreads();

    layer<4, 64, false>(Xa, Xb, w0, b0, g0, be0, m0, v0, tid);
    __syncthreads();
    layer<4, 128, false>(Xb, Xa, w1, b1, g1, be1, m1, v1, tid);
    __syncthreads();
    layer<8, 128, true>(Xa, Xb /* used as [8][256] reduce buffer */, w2, b2, g2, be2, m2, v2, tid);
    __syncthreads();

    // cross-kg max: red[kg*256 + o]
    float m = Xb[tid];
    #pragma unroll
    for (int kgi = 1; kgi < 8; ++kgi) m = fmaxf(m, Xb[kgi * 256 + tid]);
    out[(size_t)B_ * S_ * 3 + ((size_t)(b * 256 + tid)) * S_ + s] = m;
}

// ======================= launch =======================
extern "C" void kernel_launch(void* const* d_in, const int* in_sizes, int n_in,
                              void* d_out, int out_size, void* d_ws, size_t ws_size,
                              hipStream_t stream) {
    const float* xyz     = (const float*)d_in[0];
    const float* feature = (const float*)d_in[1];
    const float* w0 = (const float*)d_in[2];
    const float* b0 = (const float*)d_in[3];
    const float* g0 = (const float*)d_in[4];
    const float* be0 = (const float*)d_in[5];
    const float* m0 = (const float*)d_in[6];
    const float* v0 = (const float*)d_in[7];
    const float* w1 = (const float*)d_in[8];
    const float* b1 = (const float*)d_in[9];
    const float* g1 = (const float*)d_in[10];
    const float* be1 = (const float*)d_in[11];
    const float* m1 = (const float*)d_in[12];
    const float* v1 = (const float*)d_in[13];
    const float* w2 = (const float*)d_in[14];
    const float* b2 = (const float*)d_in[15];
    const float* g2 = (const float*)d_in[16];
    const float* be2 = (const float*)d_in[17];
    const float* m2 = (const float*)d_in[18];
    const float* v2 = (const float*)d_in[19];

    float* out = (float*)d_out;
    char*  ws  = (char*)d_ws;

    const size_t nidx_bytes  = (size_t)B_ * S_ * K_ * sizeof(int);       // 1 MiB
    const size_t featT_bytes = (size_t)B_ * N_ * C0_ * sizeof(float);    // 16 MiB
    int*   nidx  = (int*)ws;
    float* featT = (float*)(ws + (1 << 20));
    int use_featT = (ws_size >= (1 << 20) + featT_bytes) ? 1 : 0;

    float* newxyz = out;   // output 0 region: [B, S, 3]

    int ntr = use_featT ? (B_ * (N_ / 64)) : 0;   // 1024 transpose blocks
    fps_tr_kernel<<<B_ + ntr, 512, 0, stream>>>(xyz, feature, featT, newxyz);
    knn_kernel<<<B_ * S_, 256, 0, stream>>>(xyz, newxyz, nidx);
    mlp_kernel<<<B_ * S_, 256, 0, stream>>>(featT, feature, nidx,
                                            w0, b0, g0, be0, m0, v0,
                                            w1, b1, g1, be1, m1, v1,
                                            w2, b2, g2, be2, m2, v2,
                                            out, use_featT);
}

// Round 2
// 2000.386 us; speedup vs baseline: 1.6660x; 1.6660x over previous
//
#include <hip/hip_runtime.h>
#include <hip/hip_bf16.h>
#include <math.h>

#define B_  8
#define N_  8192
#define S_  1024
#define K_  32
#define C0_ 64

typedef __attribute__((ext_vector_type(8))) short short8;
typedef __attribute__((ext_vector_type(4))) float f32x4;

// ---- workspace layout (bytes) ----
#define WNELEM   57344            // 128*64 + 128*128 + 256*128 weight elements
#define WH_OFF   0                // bf16 hi weights
#define WL_OFF   114688           // bf16 lo weights
#define SC_OFF   229376           // 512 f32 scale
#define SH_OFF   231424           // 512 f32 shift
#define FTH_OFF  233728           // featT hi bf16 [B][N][64]  (8 MiB)
#define FTL_OFF  8622336          // featT lo bf16 [B][N][64]  (8 MiB)
#define WS_NEED  17010944
// per-layer element offsets into Wh/Wl
#define WL0E 0
#define WL1E 8192
#define WL2E 24576

__device__ __forceinline__ void split_bf16(float x, unsigned short& h, unsigned short& l) {
    __hip_bfloat16 hb = __float2bfloat16(x);
    float hf = __bfloat162float(hb);
    __hip_bfloat16 lb = __float2bfloat16(x - hf);
    h = *(unsigned short*)&hb;
    l = *(unsigned short*)&lb;
}

__device__ __forceinline__ f32x4 mfma16(short8 a, short8 b, f32x4 c) {
    return __builtin_amdgcn_mfma_f32_16x16x32_bf16(a, b, c, 0, 0, 0);
}

// =====================================================================
// Kernel 1: FPS (blocks 0..7) + prep roles on the otherwise-idle 248 CUs:
//   - feature transpose+bf16split  [B][64][N] -> featTh/featTl [B][N][64]
//   - weight bf16 hi/lo split
//   - BN scale/shift fold
// =====================================================================
__global__ __launch_bounds__(512) void fps_prep_kernel(
    const float* __restrict__ xyz, const float* __restrict__ feature,
    const float* __restrict__ w0, const float* __restrict__ w1, const float* __restrict__ w2,
    const float* __restrict__ b0, const float* __restrict__ g0, const float* __restrict__ be0,
    const float* __restrict__ m0, const float* __restrict__ v0,
    const float* __restrict__ b1, const float* __restrict__ g1, const float* __restrict__ be1,
    const float* __restrict__ m1, const float* __restrict__ v1,
    const float* __restrict__ b2, const float* __restrict__ g2, const float* __restrict__ be2,
    const float* __restrict__ m2, const float* __restrict__ v2,
    char* __restrict__ ws, float* __restrict__ newxyz, int use_ft)
{
    __shared__ __align__(16) float sm[3 * N_ + 32];
    const int tid = threadIdx.x;
    const int bid = (int)blockIdx.x;

    if (bid >= B_) {
        int rb = bid - B_;
        if (use_ft) {
            if (rb < 1024) {
                // ---- transpose + split role ----
                unsigned short* th = (unsigned short*)sm;        // [64][72]
                unsigned short* tl = th + 64 * 72;
                int bb = rb >> 7;
                int n0 = (rb & 127) * 64;
                {
                    int cg = tid >> 6, ln = tid & 63;
                    const float* fb = feature + (size_t)bb * C0_ * N_;
                    #pragma unroll
                    for (int i = 0; i < 8; ++i) {
                        int c = cg * 8 + i;
                        float x = fb[(size_t)c * N_ + n0 + ln];
                        unsigned short h, l;
                        split_bf16(x, h, l);
                        th[ln * 72 + c] = h;
                        tl[ln * 72 + c] = l;
                    }
                }
                __syncthreads();
                {
                    int n = tid >> 3, c0 = (tid & 7) * 8;
                    unsigned short* fth = (unsigned short*)(ws + FTH_OFF) + ((size_t)(bb * N_ + n0 + n)) * C0_ + c0;
                    unsigned short* ftl = (unsigned short*)(ws + FTL_OFF) + ((size_t)(bb * N_ + n0 + n)) * C0_ + c0;
                    *(short8*)fth = *(const short8*)(th + n * 72 + c0);
                    *(short8*)ftl = *(const short8*)(tl + n * 72 + c0);
                }
                return;
            }
            rb -= 1024;
        }
        if (rb < 112) {
            // ---- weight split role: 112*512 = 57344 elements ----
            int i = rb * 512 + tid;
            float x;
            if (i < WL1E)      x = w0[i];
            else if (i < WL2E) x = w1[i - WL1E];
            else               x = w2[i - WL2E];
            unsigned short h, l;
            split_bf16(x, h, l);
            ((unsigned short*)(ws + WH_OFF))[i] = h;
            ((unsigned short*)(ws + WL_OFF))[i] = l;
            return;
        }
        // ---- scale/shift role: 512 channels ----
        {
            int o = tid;
            const float *bb_, *gg, *be_, *mm, *vv; int oo;
            if (o < 128)      { bb_ = b0; gg = g0; be_ = be0; mm = m0; vv = v0; oo = o; }
            else if (o < 256) { bb_ = b1; gg = g1; be_ = be1; mm = m1; vv = v1; oo = o - 128; }
            else              { bb_ = b2; gg = g2; be_ = be2; mm = m2; vv = v2; oo = o - 256; }
            float scv = gg[oo] / sqrtf(vv[oo] + 1e-5f);
            ((float*)(ws + SC_OFF))[o] = scv;
            ((float*)(ws + SH_OFF))[o] = (bb_[oo] - mm[oo]) * scv + be_[oo];
        }
        return;
    }

    // ---- FPS role (exact-semantics, unchanged from round 1) ----
    const int b = bid;
    float* xs = sm;
    float* ys = sm + N_;
    float* zs = sm + 2 * N_;
    unsigned long long* wredA = (unsigned long long*)(sm + 3 * N_);
    unsigned long long* wredB = (unsigned long long*)(sm + 3 * N_ + 16);

    float px[16], py[16], pz[16], mind[16];
    const float* xb = xyz + (size_t)b * N_ * 3;
    #pragma unroll
    for (int j = 0; j < 16; ++j) {
        int n = j * 512 + tid;
        float x = xb[n * 3], y = xb[n * 3 + 1], z = xb[n * 3 + 2];
        px[j] = x; py[j] = y; pz[j] = z;
        xs[n] = x; ys[n] = y; zs[n] = z;
        mind[j] = 1e10f;
    }
    __syncthreads();

    float lx = xs[0], ly = ys[0], lz = zs[0];
    if (tid == 0) {
        float* d0 = newxyz + (size_t)b * S_ * 3;
        d0[0] = lx; d0[1] = ly; d0[2] = lz;
    }
    const int lane = tid & 63, wid = tid >> 6;

    for (int it = 1; it < S_; ++it) {
        float bv = -1.0f; int bj = 0;
        #pragma unroll
        for (int j = 0; j < 16; ++j) {
            float dx = __fsub_rn(px[j], lx);
            float dy = __fsub_rn(py[j], ly);
            float dz = __fsub_rn(pz[j], lz);
            float dd = __fadd_rn(__fadd_rn(__fmul_rn(dx, dx), __fmul_rn(dy, dy)), __fmul_rn(dz, dz));
            float mj = fminf(mind[j], dd);
            mind[j] = mj;
            if (mj > bv) { bv = mj; bj = j; }
        }
        unsigned long long best =
            ((unsigned long long)__float_as_uint(bv) << 32) |
            (unsigned long long)(0xFFFFFFFFu - (unsigned)(bj * 512 + tid));
        #pragma unroll
        for (int off = 1; off < 64; off <<= 1) {
            unsigned long long o = __shfl_xor(best, off);
            if (o > best) best = o;
        }
        unsigned long long* wred = (it & 1) ? wredA : wredB;
        if (lane == 0) wred[wid] = best;
        __syncthreads();
        unsigned long long g = wred[0];
        #pragma unroll
        for (int w = 1; w < 8; ++w) { unsigned long long o = wred[w]; if (o > g) g = o; }
        int ns = (int)(0xFFFFFFFFu - (unsigned)(g & 0xFFFFFFFFull));
        lx = xs[ns]; ly = ys[ns]; lz = zs[ns];
        if (tid == 0) {
            float* d0 = newxyz + ((size_t)b * S_ + it) * 3;
            d0[0] = lx; d0[1] = ly; d0[2] = lz;
        }
    }
}

// =====================================================================
// MFMA layer core. X LDS layout: [hi 32*136 | lo 32*136] ushort,
// row = neighbor n (32), col = channel k, stride 136 (conflict-free b128).
// Wave wv owns out-channels [wv*MT*16, (wv+1)*MT*16).
// =====================================================================
template<int MT, int KC, bool LAST>
__device__ __forceinline__ void mfma_layer(
    const unsigned short* __restrict__ Xin, unsigned short* __restrict__ Xout,
    const unsigned short* __restrict__ WhL, const unsigned short* __restrict__ WlL,
    const float* __restrict__ scL, const float* __restrict__ shL,
    float* __restrict__ outp, int wv, int ln15, int quad)
{
    const int Kdim = KC * 32;
    f32x4 acc[MT][2];
    #pragma unroll
    for (int mt = 0; mt < MT; ++mt) {
        acc[mt][0] = (f32x4){0.f, 0.f, 0.f, 0.f};
        acc[mt][1] = (f32x4){0.f, 0.f, 0.f, 0.f};
    }
    #pragma unroll
    for (int kc = 0; kc < KC; ++kc) {
        const int k0 = kc * 32 + quad * 8;
        short8 bh0 = *(const short8*)(Xin + ln15 * 136 + k0);
        short8 bh1 = *(const short8*)(Xin + (16 + ln15) * 136 + k0);
        short8 bl0 = *(const short8*)(Xin + 32 * 136 + ln15 * 136 + k0);
        short8 bl1 = *(const short8*)(Xin + 32 * 136 + (16 + ln15) * 136 + k0);
        #pragma unroll
        for (int mt = 0; mt < MT; ++mt) {
            const int row = wv * (MT * 16) + mt * 16 + ln15;
            short8 ah = *(const short8*)(WhL + (size_t)row * Kdim + k0);
            short8 al = *(const short8*)(WlL + (size_t)row * Kdim + k0);
            acc[mt][0] = mfma16(al, bh0, acc[mt][0]);
            acc[mt][0] = mfma16(ah, bl0, acc[mt][0]);
            acc[mt][0] = mfma16(ah, bh0, acc[mt][0]);
            acc[mt][1] = mfma16(al, bh1, acc[mt][1]);
            acc[mt][1] = mfma16(ah, bl1, acc[mt][1]);
            acc[mt][1] = mfma16(ah, bh1, acc[mt][1]);
        }
    }
    #pragma unroll
    for (int mt = 0; mt < MT; ++mt) {
        const int o4 = wv * (MT * 16) + mt * 16 + quad * 4;
        f32x4 scv = *(const f32x4*)(scL + o4);
        f32x4 shv = *(const f32x4*)(shL + o4);
        #pragma unroll
        for (int r = 0; r < 4; ++r) {
            float v0 = fmaxf(acc[mt][0][r] * scv[r] + shv[r], 0.f);
            float v1 = fmaxf(acc[mt][1][r] * scv[r] + shv[r], 0.f);
            if (LAST) {
                float m = fmaxf(v0, v1);
                m = fmaxf(m, __shfl_xor(m, 1));
                m = fmaxf(m, __shfl_xor(m, 2));
                m = fmaxf(m, __shfl_xor(m, 4));
                m = fmaxf(m, __shfl_xor(m, 8));
                if (ln15 == 0) outp[(size_t)(o4 + r) * S_] = m;
            } else {
                unsigned short h, l;
                split_bf16(v0, h, l);
                Xout[ln15 * 136 + o4 + r] = h;
                Xout[32 * 136 + ln15 * 136 + o4 + r] = l;
                split_bf16(v1, h, l);
                Xout[(16 + ln15) * 136 + o4 + r] = h;
                Xout[32 * 136 + (16 + ln15) * 136 + o4 + r] = l;
            }
        }
    }
}

// =====================================================================
// Kernel 2: fused kNN (exact top-32, single barrier/round) + bf16-split
// MFMA MLP + k-max. One block (256 thr / 4 waves) per (b,s).
// =====================================================================
__global__ __launch_bounds__(256) void knn_mlp_kernel(
    const float* __restrict__ xyz, const float* __restrict__ feature,
    const char* __restrict__ ws, float* __restrict__ out, int use_ft)
{
    __shared__ __align__(16) unsigned short XA[2 * 32 * 136];
    __shared__ __align__(16) unsigned short XB[2 * 32 * 136];
    __shared__ unsigned long long kslots[2][4];
    __shared__ int nid_s[K_];

    const int tid = threadIdx.x;
    const int b = blockIdx.x >> 10, s = blockIdx.x & 1023;
    const int lane = tid & 63, wid = tid >> 6;
    const int ln15 = lane & 15, quad = lane >> 4;

    // ---------- kNN ----------
    const float* q = out + (size_t)(b * S_ + s) * 3;   // newxyz lives in out
    float qx = q[0], qy = q[1], qz = q[2];
    float sa = __fadd_rn(__fadd_rn(__fmul_rn(qx, qx), __fmul_rn(qy, qy)), __fmul_rn(qz, qz));

    float d[32];
    const float* base = xyz + (size_t)b * N_ * 3;
    #pragma unroll
    for (int i = 0; i < 32; ++i) {
        int n = i * 256 + tid;
        float x = base[n * 3], y = base[n * 3 + 1], z = base[n * 3 + 2];
        float sb  = __fadd_rn(__fadd_rn(__fmul_rn(x, x), __fmul_rn(y, y)), __fmul_rn(z, z));
        float dot = __fadd_rn(__fadd_rn(__fmul_rn(qx, x), __fmul_rn(qy, y)), __fmul_rn(qz, z));
        d[i] = __fsub_rn(__fadd_rn(sa, sb), __fmul_rn(2.0f, dot));
    }
    float bd = INFINITY; int bn = 0x7fffffff;
    #pragma unroll
    for (int i = 0; i < 32; ++i) { if (d[i] < bd) { bd = d[i]; bn = i * 256 + tid; } }

    for (int r = 0; r < K_; ++r) {
        unsigned ub = __float_as_uint(bd);
        ub = (ub >> 31) ? ~ub : (ub | 0x80000000u);    // monotone total order key
        unsigned long long pk = ((unsigned long long)ub << 32) | (unsigned)bn;
        #pragma unroll
        for (int off = 1; off < 64; off <<= 1) {
            unsigned long long o = __shfl_xor(pk, off);
            if (o < pk) pk = o;
        }
        if (lane == 0) kslots[r & 1][wid] = pk;
        __syncthreads();
        unsigned long long g = kslots[r & 1][0];
        #pragma unroll
        for (int w = 1; w < 4; ++w) { unsigned long long o = kslots[r & 1][w]; if (o < g) g = o; }
        int wn = (int)(unsigned)(g & 0xFFFFFFFFull);
        if (bn == wn) {                                 // unique owner
            nid_s[r] = wn;
            int widx = wn >> 8;
            #pragma unroll
            for (int i = 0; i < 32; ++i) if (i == widx) d[i] = INFINITY;
            bd = INFINITY; bn = 0x7fffffff;
            #pragma unroll
            for (int i = 0; i < 32; ++i) { if (d[i] < bd) { bd = d[i]; bn = i * 256 + tid; } }
        }
    }
    __syncthreads();   // nid_s ready

    // ---------- gather X0 into LDS (bf16 hi/lo, [n][ch]) ----------
    {
        int k = tid >> 3, c0 = (tid & 7) * 8;
        if (use_ft) {
            const unsigned short* fh = (const unsigned short*)(ws + FTH_OFF) + ((size_t)(b * N_ + nid_s[k])) * C0_ + c0;
            const unsigned short* fl = (const unsigned short*)(ws + FTL_OFF) + ((size_t)(b * N_ + nid_s[k])) * C0_ + c0;
            *(short8*)(XA + k * 136 + c0)            = *(const short8*)fh;
            *(short8*)(XA + 32 * 136 + k * 136 + c0) = *(const short8*)fl;
        } else {
            int n = nid_s[k];
            #pragma unroll
            for (int j = 0; j < 8; ++j) {
                float x = feature[((size_t)b * C0_ + c0 + j) * N_ + n];
                unsigned short h, l;
                split_bf16(x, h, l);
                XA[k * 136 + c0 + j] = h;
                XA[32 * 136 + k * 136 + c0 + j] = l;
            }
        }
    }
    __syncthreads();

    // ---------- MLP ----------
    const unsigned short* Wh = (const unsigned short*)(ws + WH_OFF);
    const unsigned short* Wl = (const unsigned short*)(ws + WL_OFF);
    const float* sc = (const float*)(ws + SC_OFF);
    const float* sh = (const float*)(ws + SH_OFF);

    mfma_layer<2, 2, false>(XA, XB, Wh + WL0E, Wl + WL0E, sc + 0,   sh + 0,   nullptr, wid, ln15, quad);
    __syncthreads();
    mfma_layer<2, 4, false>(XB, XA, Wh + WL1E, Wl + WL1E, sc + 128, sh + 128, nullptr, wid, ln15, quad);
    __syncthreads();
    float* outp = out + (size_t)B_ * S_ * 3 + (size_t)b * 256 * S_ + s;
    mfma_layer<4, 4, true>(XA, nullptr, Wh + WL2E, Wl + WL2E, sc + 256, sh + 256, outp, wid, ln15, quad);
}

// ======================= launch =======================
extern "C" void kernel_launch(void* const* d_in, const int* in_sizes, int n_in,
                              void* d_out, int out_size, void* d_ws, size_t ws_size,
                              hipStream_t stream) {
    const float* xyz     = (const float*)d_in[0];
    const float* feature = (const float*)d_in[1];
    const float* w0 = (const float*)d_in[2];
    const float* b0 = (const float*)d_in[3];
    const float* g0 = (const float*)d_in[4];
    const float* be0 = (const float*)d_in[5];
    const float* m0 = (const float*)d_in[6];
    const float* v0 = (const float*)d_in[7];
    const float* w1 = (const float*)d_in[8];
    const float* b1 = (const float*)d_in[9];
    const float* g1 = (const float*)d_in[10];
    const float* be1 = (const float*)d_in[11];
    const float* m1 = (const float*)d_in[12];
    const float* v1 = (const float*)d_in[13];
    const float* w2 = (const float*)d_in[14];
    const float* b2 = (const float*)d_in[15];
    const float* g2 = (const float*)d_in[16];
    const float* be2 = (const float*)d_in[17];
    const float* m2 = (const float*)d_in[18];
    const float* v2 = (const float*)d_in[19];

    float* out = (float*)d_out;
    char*  ws  = (char*)d_ws;
    int use_ft = (ws_size >= (size_t)WS_NEED) ? 1 : 0;

    int nb = B_ + (use_ft ? 1024 : 0) + 112 + 1;
    fps_prep_kernel<<<nb, 512, 0, stream>>>(xyz, feature, w0, w1, w2,
        b0, g0, be0, m0, v0, b1, g1, be1, m1, v1, b2, g2, be2, m2, v2,
        ws, out /* newxyz at offset 0 */, use_ft);
    knn_mlp_kernel<<<B_ * S_, 256, 0, stream>>>(xyz, feature, (const char*)ws, out, use_ft);
}

// Round 3
// 1462.604 us; speedup vs baseline: 2.2786x; 1.3677x over previous
//
#include <hip/hip_runtime.h>
#include <hip/hip_bf16.h>
#include <math.h>

#define B_  8
#define N_  8192
#define S_  1024
#define K_  32
#define C0_ 64

typedef __attribute__((ext_vector_type(8))) short short8;
typedef __attribute__((ext_vector_type(4))) float f32x4;

// ---- workspace layout (bytes) ----
#define WH_OFF   0          // bf16 hi weights (57344 elems)
#define WL_OFF   114688     // bf16 lo weights
#define SC_OFF   229376     // 512 f32 scale
#define SH_OFF   231424     // 512 f32 shift
#define FT_OFF   233472     // featT bf16 [B][N][64] (8 MiB)
#define NIDX_OFF 8622080    // int [B][S][32] (1 MiB)
// per-layer element offsets into Wh/Wl
#define WL0E 0
#define WL1E 8192
#define WL2E 24576

__device__ __forceinline__ void split_bf16(float x, unsigned short& h, unsigned short& l) {
    __hip_bfloat16 hb = __float2bfloat16(x);
    float hf = __bfloat162float(hb);
    __hip_bfloat16 lb = __float2bfloat16(x - hf);
    h = *(unsigned short*)&hb;
    l = *(unsigned short*)&lb;
}

__device__ __forceinline__ f32x4 mfma16(short8 a, short8 b, f32x4 c) {
    return __builtin_amdgcn_mfma_f32_16x16x32_bf16(a, b, c, 0, 0, 0);
}

// =====================================================================
// Kernel 1: FPS (blocks 0..7, exact semantics) + prep roles:
//   blocks 8..1031: feature transpose -> featT bf16 [B][N][64]
//   blocks 1032..1143: weight bf16 hi/lo split
//   block 1144: BN scale/shift fold
// =====================================================================
__global__ __launch_bounds__(512) void fps_prep_kernel(
    const float* __restrict__ xyz, const float* __restrict__ feature,
    const float* __restrict__ w0, const float* __restrict__ w1, const float* __restrict__ w2,
    const float* __restrict__ b0, const float* __restrict__ g0, const float* __restrict__ be0,
    const float* __restrict__ m0, const float* __restrict__ v0,
    const float* __restrict__ b1, const float* __restrict__ g1, const float* __restrict__ be1,
    const float* __restrict__ m1, const float* __restrict__ v1,
    const float* __restrict__ b2, const float* __restrict__ g2, const float* __restrict__ be2,
    const float* __restrict__ m2, const float* __restrict__ v2,
    char* __restrict__ ws, float* __restrict__ newxyz)
{
    __shared__ __align__(16) float sm[3 * N_ + 32];
    const int tid = threadIdx.x;
    const int bid = (int)blockIdx.x;

    if (bid >= B_) {
        int rb = bid - B_;
        if (rb < 1024) {
            // ---- transpose role: [64 ch][N] -> [n][64 ch] bf16 ----
            unsigned short* th = (unsigned short*)sm;        // [64][72]
            int bb = rb >> 7;
            int n0 = (rb & 127) * 64;
            {
                int cg = tid >> 6, ln = tid & 63;
                const float* fb = feature + (size_t)bb * C0_ * N_;
                #pragma unroll
                for (int i = 0; i < 8; ++i) {
                    int c = cg * 8 + i;
                    __hip_bfloat16 hb = __float2bfloat16(fb[(size_t)c * N_ + n0 + ln]);
                    th[ln * 72 + c] = *(unsigned short*)&hb;
                }
            }
            __syncthreads();
            {
                int n = tid >> 3, c0 = (tid & 7) * 8;
                unsigned short* ft = (unsigned short*)(ws + FT_OFF) + ((size_t)(bb * N_ + n0 + n)) * C0_ + c0;
                *(short8*)ft = *(const short8*)(th + n * 72 + c0);
            }
            return;
        }
        rb -= 1024;
        if (rb < 112) {
            // ---- weight split role ----
            int i = rb * 512 + tid;
            float x;
            if (i < WL1E)      x = w0[i];
            else if (i < WL2E) x = w1[i - WL1E];
            else               x = w2[i - WL2E];
            unsigned short h, l;
            split_bf16(x, h, l);
            ((unsigned short*)(ws + WH_OFF))[i] = h;
            ((unsigned short*)(ws + WL_OFF))[i] = l;
            return;
        }
        // ---- scale/shift role: 512 channels ----
        {
            int o = tid;
            const float *bb_, *gg, *be_, *mm, *vv; int oo;
            if (o < 128)      { bb_ = b0; gg = g0; be_ = be0; mm = m0; vv = v0; oo = o; }
            else if (o < 256) { bb_ = b1; gg = g1; be_ = be1; mm = m1; vv = v1; oo = o - 128; }
            else              { bb_ = b2; gg = g2; be_ = be2; mm = m2; vv = v2; oo = o - 256; }
            float scv = gg[oo] / sqrtf(vv[oo] + 1e-5f);
            ((float*)(ws + SC_OFF))[o] = scv;
            ((float*)(ws + SH_OFF))[o] = (bb_[oo] - mm[oo]) * scv + be_[oo];
        }
        return;
    }

    // ---- FPS role (exact semantics, unchanged — known correct) ----
    const int b = bid;
    float* xs = sm;
    float* ys = sm + N_;
    float* zs = sm + 2 * N_;
    unsigned long long* wredA = (unsigned long long*)(sm + 3 * N_);
    unsigned long long* wredB = (unsigned long long*)(sm + 3 * N_ + 16);

    float px[16], py[16], pz[16], mind[16];
    const float* xb = xyz + (size_t)b * N_ * 3;
    #pragma unroll
    for (int j = 0; j < 16; ++j) {
        int n = j * 512 + tid;
        float x = xb[n * 3], y = xb[n * 3 + 1], z = xb[n * 3 + 2];
        px[j] = x; py[j] = y; pz[j] = z;
        xs[n] = x; ys[n] = y; zs[n] = z;
        mind[j] = 1e10f;
    }
    __syncthreads();

    float lx = xs[0], ly = ys[0], lz = zs[0];
    if (tid == 0) {
        float* d0 = newxyz + (size_t)b * S_ * 3;
        d0[0] = lx; d0[1] = ly; d0[2] = lz;
    }
    const int lane = tid & 63, wid = tid >> 6;

    for (int it = 1; it < S_; ++it) {
        float bv = -1.0f; int bj = 0;
        #pragma unroll
        for (int j = 0; j < 16; ++j) {
            float dx = __fsub_rn(px[j], lx);
            float dy = __fsub_rn(py[j], ly);
            float dz = __fsub_rn(pz[j], lz);
            float dd = __fadd_rn(__fadd_rn(__fmul_rn(dx, dx), __fmul_rn(dy, dy)), __fmul_rn(dz, dz));
            float mj = fminf(mind[j], dd);
            mind[j] = mj;
            if (mj > bv) { bv = mj; bj = j; }
        }
        unsigned long long best =
            ((unsigned long long)__float_as_uint(bv) << 32) |
            (unsigned long long)(0xFFFFFFFFu - (unsigned)(bj * 512 + tid));
        #pragma unroll
        for (int off = 1; off < 64; off <<= 1) {
            unsigned long long o = __shfl_xor(best, off);
            if (o > best) best = o;
        }
        unsigned long long* wred = (it & 1) ? wredA : wredB;
        if (lane == 0) wred[wid] = best;
        __syncthreads();
        unsigned long long g = wred[0];
        #pragma unroll
        for (int w = 1; w < 8; ++w) { unsigned long long o = wred[w]; if (o > g) g = o; }
        int ns = (int)(0xFFFFFFFFu - (unsigned)(g & 0xFFFFFFFFull));
        lx = xs[ns]; ly = ys[ns]; lz = zs[ns];
        if (tid == 0) {
            float* d0 = newxyz + ((size_t)b * S_ + it) * 3;
            d0[0] = lx; d0[1] = ly; d0[2] = lz;
        }
    }
}

// =====================================================================
// Kernel 2: kNN via exact radix-select. One block (256 thr) per query.
// Monotone u32 key; 2048-bin histogram of key>>21; everything in bins
// < boundary-bin is selected outright; boundary bin resolved by a small
// wave-0 (key,idx)-lexicographic tournament. Set equality with the
// reference's stable top_k is exact (max-pool is order-invariant).
// =====================================================================
#define BINS 2048
#define CCAP 256

__global__ __launch_bounds__(256) void knn_kernel(
    const float* __restrict__ xyz, const float* __restrict__ newxyz,
    int* __restrict__ nidx)
{
    __shared__ unsigned hist[BINS];
    __shared__ unsigned wpart[4];
    __shared__ int sBin, sBelow;
    __shared__ unsigned cnt_sel, cnt_cand;
    __shared__ int sel[K_];
    __shared__ unsigned long long cand[CCAP];
    __shared__ unsigned long long kslots[2][4];

    const int tid = threadIdx.x;
    const int b = blockIdx.x >> 10, s = blockIdx.x & 1023;
    const int lane = tid & 63, wid = tid >> 6;

    #pragma unroll
    for (int i = 0; i < BINS / 256; ++i) hist[tid + i * 256] = 0;
    if (tid == 0) { cnt_sel = 0; cnt_cand = 0; }

    const float* q = newxyz + (size_t)(b * S_ + s) * 3;
    float qx = q[0], qy = q[1], qz = q[2];
    float sa = __fadd_rn(__fadd_rn(__fmul_rn(qx, qx), __fmul_rn(qy, qy)), __fmul_rn(qz, qz));

    unsigned key[32];
    const float* base = xyz + (size_t)b * N_ * 3;
    #pragma unroll
    for (int i = 0; i < 32; ++i) {
        int n = i * 256 + tid;
        float x = base[n * 3], y = base[n * 3 + 1], z = base[n * 3 + 2];
        float sb  = __fadd_rn(__fadd_rn(__fmul_rn(x, x), __fmul_rn(y, y)), __fmul_rn(z, z));
        float dot = __fadd_rn(__fadd_rn(__fmul_rn(qx, x), __fmul_rn(qy, y)), __fmul_rn(qz, z));
        float d   = __fsub_rn(__fadd_rn(sa, sb), __fmul_rn(2.0f, dot));
        unsigned u = __float_as_uint(d);
        key[i] = u ^ (unsigned)(((int)u >> 31) | (int)0x80000000);   // monotone total order
    }
    __syncthreads();
    #pragma unroll
    for (int i = 0; i < 32; ++i) atomicAdd(&hist[key[i] >> 21], 1u);
    __syncthreads();

    // block scan over per-thread 8-bin groups to locate boundary bin
    unsigned h8[8];
    unsigned lsum = 0;
    #pragma unroll
    for (int i = 0; i < 8; ++i) { h8[i] = hist[tid * 8 + i]; lsum += h8[i]; }
    unsigned inc = lsum;
    #pragma unroll
    for (int off = 1; off < 64; off <<= 1) {
        unsigned o = __shfl_up(inc, off);
        if (lane >= off) inc += o;
    }
    if (lane == 63) wpart[wid] = inc;
    __syncthreads();
    unsigned basec = 0;
    #pragma unroll
    for (int w = 0; w < 4; ++w) if (w < wid) basec += wpart[w];
    unsigned excl = basec + inc - lsum;
    if (excl < (unsigned)K_ && excl + lsum >= (unsigned)K_) {
        unsigned c = excl;
        #pragma unroll
        for (int i = 0; i < 8; ++i) {
            if (c < (unsigned)K_ && c + h8[i] >= (unsigned)K_) { sBin = tid * 8 + i; sBelow = (int)c; }
            c += h8[i];
        }
    }
    __syncthreads();
    const unsigned Bbin = (unsigned)sBin;
    const int below = sBelow;

    #pragma unroll
    for (int i = 0; i < 32; ++i) {
        unsigned bin = key[i] >> 21;
        int n = i * 256 + tid;
        if (bin < Bbin) {
            unsigned p = atomicAdd(&cnt_sel, 1u);
            if (p < (unsigned)K_) sel[p] = n;
        } else if (bin == Bbin) {
            unsigned p = atomicAdd(&cnt_cand, 1u);
            if (p < CCAP) cand[p] = ((unsigned long long)key[i] << 32) | (unsigned)n;
        }
    }
    __syncthreads();

    const int m = (int)cnt_cand;
    const int mtake = K_ - below;
    if (m <= CCAP) {
        if (wid == 0) {
            unsigned long long v[4];
            #pragma unroll
            for (int j = 0; j < 4; ++j) {
                int p = lane + j * 64;
                v[j] = (p < m) ? cand[p] : ~0ull;
            }
            for (int r = 0; r < mtake; ++r) {
                unsigned long long loc = v[0];
                #pragma unroll
                for (int j = 1; j < 4; ++j) if (v[j] < loc) loc = v[j];
                unsigned long long g = loc;
                #pragma unroll
                for (int off = 1; off < 64; off <<= 1) {
                    unsigned long long o = __shfl_xor(g, off);
                    if (o < g) g = o;
                }
                #pragma unroll
                for (int j = 0; j < 4; ++j) if (v[j] == g) v[j] = ~0ull;
                if (lane == 0) sel[below + r] = (int)(unsigned)(g & 0xFFFFFFFFull);
            }
        }
        __syncthreads();
    } else {
        // fallback (degenerate tie pile-up): exact 32-round block tournament
        unsigned bk = 0xFFFFFFFFu; int bi = 0;
        #pragma unroll
        for (int i = 0; i < 32; ++i) if (key[i] < bk) { bk = key[i]; bi = i; }
        for (int r = 0; r < K_; ++r) {
            unsigned long long pk = ((unsigned long long)bk << 32) | (unsigned)(bi * 256 + tid);
            #pragma unroll
            for (int off = 1; off < 64; off <<= 1) {
                unsigned long long o = __shfl_xor(pk, off);
                if (o < pk) pk = o;
            }
            if (lane == 0) kslots[r & 1][wid] = pk;
            __syncthreads();
            unsigned long long g = kslots[r & 1][0];
            #pragma unroll
            for (int w = 1; w < 4; ++w) { unsigned long long o = kslots[r & 1][w]; if (o < g) g = o; }
            int wn = (int)(unsigned)(g & 0xFFFFFFFFull);
            if (tid == 0) sel[r] = wn;
            if ((wn & 255) == tid) {
                int iw = wn >> 8;
                #pragma unroll
                for (int ii = 0; ii < 32; ++ii) if (ii == iw) key[ii] = 0xFFFFFFFFu;
                bk = 0xFFFFFFFFu; bi = 0;
                #pragma unroll
                for (int ii = 0; ii < 32; ++ii) if (key[ii] < bk) { bk = key[ii]; bi = ii; }
            }
        }
        __syncthreads();
    }
    if (tid < K_) nidx[((size_t)(b * S_ + s)) * K_ + tid] = sel[tid];
}

// =====================================================================
// Kernel 3: MLP, 4 queries (128 B-rows) per block, 256 thr / 4 waves.
// X single bf16 in LDS; W hi/lo split (2-term MFMA). Wave owns AF
// 16-row A-tiles; 8 B-frags reuse each weight fragment.
// =====================================================================
template<int AF, int KC, bool LAST>
__device__ __forceinline__ void layer(
    const unsigned short* __restrict__ Xin, int rsi,
    unsigned short* __restrict__ Xout,
    const unsigned short* __restrict__ Wh, const unsigned short* __restrict__ Wl,
    const float* __restrict__ sc, const float* __restrict__ sh,
    float* __restrict__ outg, int wid, int ln15, int quad)
{
    const int K = KC * 32;
    f32x4 acc[AF][8];
    #pragma unroll
    for (int a = 0; a < AF; ++a)
        #pragma unroll
        for (int j = 0; j < 8; ++j) acc[a][j] = (f32x4){0.f, 0.f, 0.f, 0.f};

    #pragma unroll
    for (int kc = 0; kc < KC; ++kc) {
        const int k0 = kc * 32 + quad * 8;
        short8 bf[8];
        #pragma unroll
        for (int j = 0; j < 8; ++j)
            bf[j] = *(const short8*)(Xin + (j * 16 + ln15) * rsi + k0);
        #pragma unroll
        for (int a = 0; a < AF; ++a) {
            const int row = wid * (AF * 16) + a * 16 + ln15;
            short8 ah = *(const short8*)(Wh + (size_t)row * K + k0);
            short8 al = *(const short8*)(Wl + (size_t)row * K + k0);
            #pragma unroll
            for (int j = 0; j < 8; ++j) {
                acc[a][j] = mfma16(al, bf[j], acc[a][j]);
                acc[a][j] = mfma16(ah, bf[j], acc[a][j]);
            }
        }
    }
    #pragma unroll
    for (int a = 0; a < AF; ++a) {
        const int o4 = wid * (AF * 16) + a * 16 + quad * 4;
        f32x4 scv = *(const f32x4*)(sc + o4);
        f32x4 shv = *(const f32x4*)(sh + o4);
        if (LAST) {
            #pragma unroll
            for (int qq = 0; qq < 4; ++qq) {
                float m4[4];
                #pragma unroll
                for (int r = 0; r < 4; ++r) {
                    float v0 = fmaxf(acc[a][2 * qq][r]     * scv[r] + shv[r], 0.f);
                    float v1 = fmaxf(acc[a][2 * qq + 1][r] * scv[r] + shv[r], 0.f);
                    float mm = fmaxf(v0, v1);
                    mm = fmaxf(mm, __shfl_xor(mm, 1));
                    mm = fmaxf(mm, __shfl_xor(mm, 2));
                    mm = fmaxf(mm, __shfl_xor(mm, 4));
                    mm = fmaxf(mm, __shfl_xor(mm, 8));
                    m4[r] = mm;
                }
                if (ln15 == 0) {
                    #pragma unroll
                    for (int r = 0; r < 4; ++r)
                        outg[(size_t)(o4 + r) * S_ + qq] = m4[r];
                }
            }
        } else {
            #pragma unroll
            for (int j = 0; j < 8; ++j) {
                unsigned short p[4];
                #pragma unroll
                for (int r = 0; r < 4; ++r) {
                    float v = fmaxf(acc[a][j][r] * scv[r] + shv[r], 0.f);
                    __hip_bfloat16 hb = __float2bfloat16(v);
                    p[r] = *(unsigned short*)&hb;
                }
                *(unsigned long long*)(Xout + (j * 16 + ln15) * 136 + o4) = *(unsigned long long*)p;
            }
        }
    }
}

__global__ __launch_bounds__(256, 2) void mlp_kernel(
    const char* __restrict__ ws, float* __restrict__ out)
{
    __shared__ __align__(16) unsigned short XA[128 * 136];
    __shared__ __align__(16) unsigned short XB[128 * 136];
    __shared__ int nid[128];

    const int tid = threadIdx.x;
    const int b = blockIdx.x >> 8;
    const int s0 = (blockIdx.x & 255) * 4;
    const int lane = tid & 63, wid = tid >> 6;
    const int ln15 = lane & 15, quad = lane >> 4;

    const int* nidx = (const int*)(ws + NIDX_OFF);
    if (tid < 128) nid[tid] = nidx[((size_t)(b * S_ + s0)) * K_ + tid];
    __syncthreads();

    const unsigned short* FT = (const unsigned short*)(ws + FT_OFF);
    #pragma unroll
    for (int it = 0; it < 4; ++it) {
        int idx = it * 256 + tid;
        int row = idx >> 3, slot = idx & 7;
        short8 v = *(const short8*)(FT + ((size_t)(b * N_ + nid[row])) * C0_ + slot * 8);
        *(short8*)(XA + row * 72 + slot * 8) = v;
    }
    __syncthreads();

    const unsigned short* Wh = (const unsigned short*)(ws + WH_OFF);
    const unsigned short* Wl = (const unsigned short*)(ws + WL_OFF);
    const float* sc = (const float*)(ws + SC_OFF);
    const float* sh = (const float*)(ws + SH_OFF);

    layer<2, 2, false>(XA, 72,  XB, Wh + WL0E, Wl + WL0E, sc,       sh,       nullptr, wid, ln15, quad);
    __syncthreads();
    layer<2, 4, false>(XB, 136, XA, Wh + WL1E, Wl + WL1E, sc + 128, sh + 128, nullptr, wid, ln15, quad);
    __syncthreads();
    float* outg = out + (size_t)B_ * S_ * 3 + (size_t)b * 256 * S_ + s0;
    layer<4, 4, true>(XA, 136, nullptr, Wh + WL2E, Wl + WL2E, sc + 256, sh + 256, outg, wid, ln15, quad);
}

// ======================= launch =======================
extern "C" void kernel_launch(void* const* d_in, const int* in_sizes, int n_in,
                              void* d_out, int out_size, void* d_ws, size_t ws_size,
                              hipStream_t stream) {
    const float* xyz     = (const float*)d_in[0];
    const float* feature = (const float*)d_in[1];
    const float* w0 = (const float*)d_in[2];
    const float* b0 = (const float*)d_in[3];
    const float* g0 = (const float*)d_in[4];
    const float* be0 = (const float*)d_in[5];
    const float* m0 = (const float*)d_in[6];
    const float* v0 = (const float*)d_in[7];
    const float* w1 = (const float*)d_in[8];
    const float* b1 = (const float*)d_in[9];
    const float* g1 = (const float*)d_in[10];
    const float* be1 = (const float*)d_in[11];
    const float* m1 = (const float*)d_in[12];
    const float* v1 = (const float*)d_in[13];
    const float* w2 = (const float*)d_in[14];
    const float* b2 = (const float*)d_in[15];
    const float* g2 = (const float*)d_in[16];
    const float* be2 = (const float*)d_in[17];
    const float* m2 = (const float*)d_in[18];
    const float* v2 = (const float*)d_in[19];

    float* out = (float*)d_out;
    char*  ws  = (char*)d_ws;

    fps_prep_kernel<<<B_ + 1024 + 112 + 1, 512, 0, stream>>>(xyz, feature, w0, w1, w2,
        b0, g0, be0, m0, v0, b1, g1, be1, m1, v1, b2, g2, be2, m2, v2,
        ws, out /* newxyz at offset 0 */);
    knn_kernel<<<B_ * S_, 256, 0, stream>>>(xyz, out, (int*)(ws + NIDX_OFF));
    mlp_kernel<<<B_ * S_ / 4, 256, 0, stream>>>((const char*)ws, out);
}

// Round 4
// 1322.506 us; speedup vs baseline: 2.5200x; 1.1059x over previous
//
#include <hip/hip_runtime.h>
#include <hip/hip_bf16.h>
#include <math.h>

#define B_  8
#define N_  8192
#define S_  1024
#define K_  32
#define C0_ 64

typedef __attribute__((ext_vector_type(8))) short short8;
typedef __attribute__((ext_vector_type(4))) float f32x4;

// ---- workspace layout (bytes) ----
#define WH_OFF   0          // bf16 hi weights (57344 elems)
#define WL_OFF   114688     // bf16 lo weights
#define SC_OFF   229376     // 512 f32 scale
#define SH_OFF   231424     // 512 f32 shift
#define FT_OFF   233472     // featT bf16 [B][N][64] (8 MiB)
#define NIDX_OFF 8622080    // int [B][S][32] (1 MiB)
// per-layer element offsets into Wh/Wl
#define WL0E 0
#define WL1E 8192
#define WL2E 24576

__device__ __forceinline__ void split_bf16(float x, unsigned short& h, unsigned short& l) {
    __hip_bfloat16 hb = __float2bfloat16(x);
    float hf = __bfloat162float(hb);
    __hip_bfloat16 lb = __float2bfloat16(x - hf);
    h = *(unsigned short*)&hb;
    l = *(unsigned short*)&lb;
}

__device__ __forceinline__ f32x4 mfma16(short8 a, short8 b, f32x4 c) {
    return __builtin_amdgcn_mfma_f32_16x16x32_bf16(a, b, c, 0, 0, 0);
}

// one DPP max-combine step on a monotone u64 key (keys > 0; old=0 is identity)
template<int CTRL, int RMASK>
__device__ __forceinline__ unsigned long long dpp_max_step(unsigned long long k) {
    unsigned lo = (unsigned)k, hi = (unsigned)(k >> 32);
    unsigned tlo = (unsigned)__builtin_amdgcn_update_dpp(0, (int)lo, CTRL, RMASK, 0xF, false);
    unsigned thi = (unsigned)__builtin_amdgcn_update_dpp(0, (int)hi, CTRL, RMASK, 0xF, false);
    unsigned long long t = ((unsigned long long)thi << 32) | (unsigned long long)tlo;
    return (t > k) ? t : k;
}

// full 64-lane max; result valid in lane 63 (VALU-pipe DPP, no LDS hops)
__device__ __forceinline__ unsigned long long wave_max_u64(unsigned long long k) {
    k = dpp_max_step<0x111, 0xF>(k);   // row_shr:1
    k = dpp_max_step<0x112, 0xF>(k);   // row_shr:2
    k = dpp_max_step<0x114, 0xF>(k);   // row_shr:4
    k = dpp_max_step<0x118, 0xF>(k);   // row_shr:8
    k = dpp_max_step<0x142, 0xA>(k);   // row_bcast:15 -> rows 1,3
    k = dpp_max_step<0x143, 0xC>(k);   // row_bcast:31 -> rows 2,3
    return k;
}

__device__ __forceinline__ unsigned long long umax64(unsigned long long a, unsigned long long b) {
    return (a > b) ? a : b;
}

// =====================================================================
// Kernel 1: FPS (blocks 0..7, exact semantics) + prep roles:
//   blocks 8..1031: feature transpose -> featT bf16 [B][N][64]
//   blocks 1032..1143: weight bf16 hi/lo split
//   block 1144: BN scale/shift fold
// =====================================================================
__global__ __launch_bounds__(512) void fps_prep_kernel(
    const float* __restrict__ xyz, const float* __restrict__ feature,
    const float* __restrict__ w0, const float* __restrict__ w1, const float* __restrict__ w2,
    const float* __restrict__ b0, const float* __restrict__ g0, const float* __restrict__ be0,
    const float* __restrict__ m0, const float* __restrict__ v0,
    const float* __restrict__ b1, const float* __restrict__ g1, const float* __restrict__ be1,
    const float* __restrict__ m1, const float* __restrict__ v1,
    const float* __restrict__ b2, const float* __restrict__ g2, const float* __restrict__ be2,
    const float* __restrict__ m2, const float* __restrict__ v2,
    char* __restrict__ ws, float* __restrict__ newxyz)
{
    __shared__ __align__(16) char smraw[N_ * 16 + 128];   // FPS: float4 xyzw[8192] + wred slots
    const int tid = threadIdx.x;
    const int bid = (int)blockIdx.x;

    if (bid >= B_) {
        int rb = bid - B_;
        if (rb < 1024) {
            // ---- transpose role: [64 ch][N] -> [n][64 ch] bf16 ----
            unsigned short* th = (unsigned short*)smraw;     // [64][72]
            int bb = rb >> 7;
            int n0 = (rb & 127) * 64;
            {
                int cg = tid >> 6, ln = tid & 63;
                const float* fb = feature + (size_t)bb * C0_ * N_;
                #pragma unroll
                for (int i = 0; i < 8; ++i) {
                    int c = cg * 8 + i;
                    __hip_bfloat16 hb = __float2bfloat16(fb[(size_t)c * N_ + n0 + ln]);
                    th[ln * 72 + c] = *(unsigned short*)&hb;
                }
            }
            __syncthreads();
            {
                int n = tid >> 3, c0 = (tid & 7) * 8;
                unsigned short* ft = (unsigned short*)(ws + FT_OFF) + ((size_t)(bb * N_ + n0 + n)) * C0_ + c0;
                *(short8*)ft = *(const short8*)(th + n * 72 + c0);
            }
            return;
        }
        rb -= 1024;
        if (rb < 112) {
            // ---- weight split role ----
            int i = rb * 512 + tid;
            float x;
            if (i < WL1E)      x = w0[i];
            else if (i < WL2E) x = w1[i - WL1E];
            else               x = w2[i - WL2E];
            unsigned short h, l;
            split_bf16(x, h, l);
            ((unsigned short*)(ws + WH_OFF))[i] = h;
            ((unsigned short*)(ws + WL_OFF))[i] = l;
            return;
        }
        // ---- scale/shift role: 512 channels ----
        {
            int o = tid;
            const float *bb_, *gg, *be_, *mm, *vv; int oo;
            if (o < 128)      { bb_ = b0; gg = g0; be_ = be0; mm = m0; vv = v0; oo = o; }
            else if (o < 256) { bb_ = b1; gg = g1; be_ = be1; mm = m1; vv = v1; oo = o - 128; }
            else              { bb_ = b2; gg = g2; be_ = be2; mm = m2; vv = v2; oo = o - 256; }
            float scv = gg[oo] / sqrtf(vv[oo] + 1e-5f);
            ((float*)(ws + SC_OFF))[o] = scv;
            ((float*)(ws + SH_OFF))[o] = (bb_[oo] - mm[oo]) * scv + be_[oo];
        }
        return;
    }

    // ---- FPS role: exact reference semantics; DPP wave-reduce (VALU pipe),
    //      float4 LDS broadcast, tree cross-wave combine ----
    const int b = bid;
    float4* xyzw = (float4*)smraw;
    unsigned long long* wredA = (unsigned long long*)(smraw + N_ * 16);
    unsigned long long* wredB = wredA + 8;

    float px[16], py[16], pz[16], mind[16];
    const float* xb = xyz + (size_t)b * N_ * 3;
    #pragma unroll
    for (int j = 0; j < 16; ++j) {
        int n = j * 512 + tid;
        float x = xb[n * 3], y = xb[n * 3 + 1], z = xb[n * 3 + 2];
        px[j] = x; py[j] = y; pz[j] = z;
        xyzw[n] = make_float4(x, y, z, 0.f);
        mind[j] = 1e10f;
    }
    __syncthreads();

    float4 p0 = xyzw[0];
    float lx = p0.x, ly = p0.y, lz = p0.z;
    if (tid == 0) {
        float* d0 = newxyz + (size_t)b * S_ * 3;
        d0[0] = lx; d0[1] = ly; d0[2] = lz;
    }
    const int lane = tid & 63, wid = tid >> 6;

    for (int it = 1; it < S_; ++it) {
        // update min-distances, track local argmax (first occurrence on ties)
        float bv = -1.0f; int bj = 0;
        #pragma unroll
        for (int j = 0; j < 16; ++j) {
            float dx = __fsub_rn(px[j], lx);
            float dy = __fsub_rn(py[j], ly);
            float dz = __fsub_rn(pz[j], lz);
            float dd = __fadd_rn(__fadd_rn(__fmul_rn(dx, dx), __fmul_rn(dy, dy)), __fmul_rn(dz, dz));
            float mj = fminf(mind[j], dd);
            mind[j] = mj;
            if (mj > bv) { bv = mj; bj = j; }
        }
        // monotone key: high = float bits (mind >= 0), low = ~n so ties pick smallest n
        unsigned long long key =
            ((unsigned long long)__float_as_uint(bv) << 32) |
            (unsigned long long)(0xFFFFFFFFu - (unsigned)(bj * 512 + tid));
        key = wave_max_u64(key);                 // lane 63 has wave max
        unsigned long long* wred = (it & 1) ? wredA : wredB;
        if (lane == 63) wred[wid] = key;
        __syncthreads();
        // all threads: tree-combine the 8 wave maxima (broadcast LDS reads)
        unsigned long long g0v = umax64(wred[0], wred[1]);
        unsigned long long g1v = umax64(wred[2], wred[3]);
        unsigned long long g2v = umax64(wred[4], wred[5]);
        unsigned long long g3v = umax64(wred[6], wred[7]);
        unsigned long long g = umax64(umax64(g0v, g1v), umax64(g2v, g3v));
        int ns = (int)(0xFFFFFFFFu - (unsigned)(g & 0xFFFFFFFFull));
        float4 p = xyzw[ns];
        lx = p.x; ly = p.y; lz = p.z;
        if (tid == 0) {
            float* d0 = newxyz + ((size_t)b * S_ + it) * 3;
            d0[0] = lx; d0[1] = ly; d0[2] = lz;
        }
    }
}

// =====================================================================
// Kernel 2: kNN via exact radix-select. One block (256 thr) per query.
// =====================================================================
#define BINS 2048
#define CCAP 256

__global__ __launch_bounds__(256) void knn_kernel(
    const float* __restrict__ xyz, const float* __restrict__ newxyz,
    int* __restrict__ nidx)
{
    __shared__ unsigned hist[BINS];
    __shared__ unsigned wpart[4];
    __shared__ int sBin, sBelow;
    __shared__ unsigned cnt_sel, cnt_cand;
    __shared__ int sel[K_];
    __shared__ unsigned long long cand[CCAP];
    __shared__ unsigned long long kslots[2][4];

    const int tid = threadIdx.x;
    const int b = blockIdx.x >> 10, s = blockIdx.x & 1023;
    const int lane = tid & 63, wid = tid >> 6;

    #pragma unroll
    for (int i = 0; i < BINS / 256; ++i) hist[tid + i * 256] = 0;
    if (tid == 0) { cnt_sel = 0; cnt_cand = 0; }

    const float* q = newxyz + (size_t)(b * S_ + s) * 3;
    float qx = q[0], qy = q[1], qz = q[2];
    float sa = __fadd_rn(__fadd_rn(__fmul_rn(qx, qx), __fmul_rn(qy, qy)), __fmul_rn(qz, qz));

    unsigned key[32];
    const float* base = xyz + (size_t)b * N_ * 3;
    #pragma unroll
    for (int i = 0; i < 32; ++i) {
        int n = i * 256 + tid;
        float x = base[n * 3], y = base[n * 3 + 1], z = base[n * 3 + 2];
        float sb  = __fadd_rn(__fadd_rn(__fmul_rn(x, x), __fmul_rn(y, y)), __fmul_rn(z, z));
        float dot = __fadd_rn(__fadd_rn(__fmul_rn(qx, x), __fmul_rn(qy, y)), __fmul_rn(qz, z));
        float d   = __fsub_rn(__fadd_rn(sa, sb), __fmul_rn(2.0f, dot));
        unsigned u = __float_as_uint(d);
        key[i] = u ^ (unsigned)(((int)u >> 31) | (int)0x80000000);   // monotone total order
    }
    __syncthreads();
    #pragma unroll
    for (int i = 0; i < 32; ++i) atomicAdd(&hist[key[i] >> 21], 1u);
    __syncthreads();

    unsigned h8[8];
    unsigned lsum = 0;
    #pragma unroll
    for (int i = 0; i < 8; ++i) { h8[i] = hist[tid * 8 + i]; lsum += h8[i]; }
    unsigned inc = lsum;
    #pragma unroll
    for (int off = 1; off < 64; off <<= 1) {
        unsigned o = __shfl_up(inc, off);
        if (lane >= off) inc += o;
    }
    if (lane == 63) wpart[wid] = inc;
    __syncthreads();
    unsigned basec = 0;
    #pragma unroll
    for (int w = 0; w < 4; ++w) if (w < wid) basec += wpart[w];
    unsigned excl = basec + inc - lsum;
    if (excl < (unsigned)K_ && excl + lsum >= (unsigned)K_) {
        unsigned c = excl;
        #pragma unroll
        for (int i = 0; i < 8; ++i) {
            if (c < (unsigned)K_ && c + h8[i] >= (unsigned)K_) { sBin = tid * 8 + i; sBelow = (int)c; }
            c += h8[i];
        }
    }
    __syncthreads();
    const unsigned Bbin = (unsigned)sBin;
    const int below = sBelow;

    #pragma unroll
    for (int i = 0; i < 32; ++i) {
        unsigned bin = key[i] >> 21;
        int n = i * 256 + tid;
        if (bin < Bbin) {
            unsigned p = atomicAdd(&cnt_sel, 1u);
            if (p < (unsigned)K_) sel[p] = n;
        } else if (bin == Bbin) {
            unsigned p = atomicAdd(&cnt_cand, 1u);
            if (p < CCAP) cand[p] = ((unsigned long long)key[i] << 32) | (unsigned)n;
        }
    }
    __syncthreads();

    const int m = (int)cnt_cand;
    const int mtake = K_ - below;
    if (m <= CCAP) {
        if (wid == 0) {
            unsigned long long v[4];
            #pragma unroll
            for (int j = 0; j < 4; ++j) {
                int p = lane + j * 64;
                v[j] = (p < m) ? cand[p] : ~0ull;
            }
            for (int r = 0; r < mtake; ++r) {
                unsigned long long loc = v[0];
                #pragma unroll
                for (int j = 1; j < 4; ++j) if (v[j] < loc) loc = v[j];
                unsigned long long g = loc;
                #pragma unroll
                for (int off = 1; off < 64; off <<= 1) {
                    unsigned long long o = __shfl_xor(g, off);
                    if (o < g) g = o;
                }
                #pragma unroll
                for (int j = 0; j < 4; ++j) if (v[j] == g) v[j] = ~0ull;
                if (lane == 0) sel[below + r] = (int)(unsigned)(g & 0xFFFFFFFFull);
            }
        }
        __syncthreads();
    } else {
        unsigned bk = 0xFFFFFFFFu; int bi = 0;
        #pragma unroll
        for (int i = 0; i < 32; ++i) if (key[i] < bk) { bk = key[i]; bi = i; }
        for (int r = 0; r < K_; ++r) {
            unsigned long long pk = ((unsigned long long)bk << 32) | (unsigned)(bi * 256 + tid);
            #pragma unroll
            for (int off = 1; off < 64; off <<= 1) {
                unsigned long long o = __shfl_xor(pk, off);
                if (o < pk) pk = o;
            }
            if (lane == 0) kslots[r & 1][wid] = pk;
            __syncthreads();
            unsigned long long g = kslots[r & 1][0];
            #pragma unroll
            for (int w = 1; w < 4; ++w) { unsigned long long o = kslots[r & 1][w]; if (o < g) g = o; }
            int wn = (int)(unsigned)(g & 0xFFFFFFFFull);
            if (tid == 0) sel[r] = wn;
            if ((wn & 255) == tid) {
                int iw = wn >> 8;
                #pragma unroll
                for (int ii = 0; ii < 32; ++ii) if (ii == iw) key[ii] = 0xFFFFFFFFu;
                bk = 0xFFFFFFFFu; bi = 0;
                #pragma unroll
                for (int ii = 0; ii < 32; ++ii) if (key[ii] < bk) { bk = key[ii]; bi = ii; }
            }
        }
        __syncthreads();
    }
    if (tid < K_) nidx[((size_t)(b * S_ + s)) * K_ + tid] = sel[tid];
}

// =====================================================================
// Kernel 3: MLP, 4 queries (128 B-rows) per block, 256 thr / 4 waves.
// =====================================================================
template<int AF, int KC, bool LAST>
__device__ __forceinline__ void layer(
    const unsigned short* __restrict__ Xin, int rsi,
    unsigned short* __restrict__ Xout,
    const unsigned short* __restrict__ Wh, const unsigned short* __restrict__ Wl,
    const float* __restrict__ sc, const float* __restrict__ sh,
    float* __restrict__ outg, int wid, int ln15, int quad)
{
    const int K = KC * 32;
    f32x4 acc[AF][8];
    #pragma unroll
    for (int a = 0; a < AF; ++a)
        #pragma unroll
        for (int j = 0; j < 8; ++j) acc[a][j] = (f32x4){0.f, 0.f, 0.f, 0.f};

    #pragma unroll
    for (int kc = 0; kc < KC; ++kc) {
        const int k0 = kc * 32 + quad * 8;
        short8 bf[8];
        #pragma unroll
        for (int j = 0; j < 8; ++j)
            bf[j] = *(const short8*)(Xin + (j * 16 + ln15) * rsi + k0);
        #pragma unroll
        for (int a = 0; a < AF; ++a) {
            const int row = wid * (AF * 16) + a * 16 + ln15;
            short8 ah = *(const short8*)(Wh + (size_t)row * K + k0);
            short8 al = *(const short8*)(Wl + (size_t)row * K + k0);
            #pragma unroll
            for (int j = 0; j < 8; ++j) {
                acc[a][j] = mfma16(al, bf[j], acc[a][j]);
                acc[a][j] = mfma16(ah, bf[j], acc[a][j]);
            }
        }
    }
    #pragma unroll
    for (int a = 0; a < AF; ++a) {
        const int o4 = wid * (AF * 16) + a * 16 + quad * 4;
        f32x4 scv = *(const f32x4*)(sc + o4);
        f32x4 shv = *(const f32x4*)(sh + o4);
        if (LAST) {
            #pragma unroll
            for (int qq = 0; qq < 4; ++qq) {
                float m4[4];
                #pragma unroll
                for (int r = 0; r < 4; ++r) {
                    float v0 = fmaxf(acc[a][2 * qq][r]     * scv[r] + shv[r], 0.f);
                    float v1 = fmaxf(acc[a][2 * qq + 1][r] * scv[r] + shv[r], 0.f);
                    float mm = fmaxf(v0, v1);
                    mm = fmaxf(mm, __shfl_xor(mm, 1));
                    mm = fmaxf(mm, __shfl_xor(mm, 2));
                    mm = fmaxf(mm, __shfl_xor(mm, 4));
                    mm = fmaxf(mm, __shfl_xor(mm, 8));
                    m4[r] = mm;
                }
                if (ln15 == 0) {
                    #pragma unroll
                    for (int r = 0; r < 4; ++r)
                        outg[(size_t)(o4 + r) * S_ + qq] = m4[r];
                }
            }
        } else {
            #pragma unroll
            for (int j = 0; j < 8; ++j) {
                unsigned short p[4];
                #pragma unroll
                for (int r = 0; r < 4; ++r) {
                    float v = fmaxf(acc[a][j][r] * scv[r] + shv[r], 0.f);
                    __hip_bfloat16 hb = __float2bfloat16(v);
                    p[r] = *(unsigned short*)&hb;
                }
                *(unsigned long long*)(Xout + (j * 16 + ln15) * 136 + o4) = *(unsigned long long*)p;
            }
        }
    }
}

__global__ __launch_bounds__(256, 2) void mlp_kernel(
    const char* __restrict__ ws, float* __restrict__ out)
{
    __shared__ __align__(16) unsigned short XA[128 * 136];
    __shared__ __align__(16) unsigned short XB[128 * 136];
    __shared__ int nid[128];

    const int tid = threadIdx.x;
    const int b = blockIdx.x >> 8;
    const int s0 = (blockIdx.x & 255) * 4;
    const int lane = tid & 63, wid = tid >> 6;
    const int ln15 = lane & 15, quad = lane >> 4;

    const int* nidx = (const int*)(ws + NIDX_OFF);
    if (tid < 128) nid[tid] = nidx[((size_t)(b * S_ + s0)) * K_ + tid];
    __syncthreads();

    const unsigned short* FT = (const unsigned short*)(ws + FT_OFF);
    #pragma unroll
    for (int it = 0; it < 4; ++it) {
        int idx = it * 256 + tid;
        int row = idx >> 3, slot = idx & 7;
        short8 v = *(const short8*)(FT + ((size_t)(b * N_ + nid[row])) * C0_ + slot * 8);
        *(short8*)(XA + row * 72 + slot * 8) = v;
    }
    __syncthreads();

    const unsigned short* Wh = (const unsigned short*)(ws + WH_OFF);
    const unsigned short* Wl = (const unsigned short*)(ws + WL_OFF);
    const float* sc = (const float*)(ws + SC_OFF);
    const float* sh = (const float*)(ws + SH_OFF);

    layer<2, 2, false>(XA, 72,  XB, Wh + WL0E, Wl + WL0E, sc,       sh,       nullptr, wid, ln15, quad);
    __syncthreads();
    layer<2, 4, false>(XB, 136, XA, Wh + WL1E, Wl + WL1E, sc + 128, sh + 128, nullptr, wid, ln15, quad);
    __syncthreads();
    float* outg = out + (size_t)B_ * S_ * 3 + (size_t)b * 256 * S_ + s0;
    layer<4, 4, true>(XA, 136, nullptr, Wh + WL2E, Wl + WL2E, sc + 256, sh + 256, outg, wid, ln15, quad);
}

// ======================= launch =======================
extern "C" void kernel_launch(void* const* d_in, const int* in_sizes, int n_in,
                              void* d_out, int out_size, void* d_ws, size_t ws_size,
                              hipStream_t stream) {
    const float* xyz     = (const float*)d_in[0];
    const float* feature = (const float*)d_in[1];
    const float* w0 = (const float*)d_in[2];
    const float* b0 = (const float*)d_in[3];
    const float* g0 = (const float*)d_in[4];
    const float* be0 = (const float*)d_in[5];
    const float* m0 = (const float*)d_in[6];
    const float* v0 = (const float*)d_in[7];
    const float* w1 = (const float*)d_in[8];
    const float* b1 = (const float*)d_in[9];
    const float* g1 = (const float*)d_in[10];
    const float* be1 = (const float*)d_in[11];
    const float* m1 = (const float*)d_in[12];
    const float* v1 = (const float*)d_in[13];
    const float* w2 = (const float*)d_in[14];
    const float* b2 = (const float*)d_in[15];
    const float* g2 = (const float*)d_in[16];
    const float* be2 = (const float*)d_in[17];
    const float* m2 = (const float*)d_in[18];
    const float* v2 = (const float*)d_in[19];

    float* out = (float*)d_out;
    char*  ws  = (char*)d_ws;

    fps_prep_kernel<<<B_ + 1024 + 112 + 1, 512, 0, stream>>>(xyz, feature, w0, w1, w2,
        b0, g0, be0, m0, v0, b1, g1, be1, m1, v1, b2, g2, be2, m2, v2,
        ws, out /* newxyz at offset 0 */);
    knn_kernel<<<B_ * S_, 256, 0, stream>>>(xyz, out, (int*)(ws + NIDX_OFF));
    mlp_kernel<<<B_ * S_ / 4, 256, 0, stream>>>((const char*)ws, out);
}